// Round 18
// baseline (202.883 us; speedup 1.0000x reference)
//
#include <hip/hip_runtime.h>

// ---------- types & helpers ----------
typedef unsigned short u16;
typedef float   f32x4  __attribute__((ext_vector_type(4)));
typedef short   short8 __attribute__((ext_vector_type(8)));
typedef __bf16  bf16x8 __attribute__((ext_vector_type(8)));
typedef float   float4v __attribute__((ext_vector_type(4)));
typedef unsigned short u16x4 __attribute__((ext_vector_type(4)));

// native HW bf16 convert (RNE) — do not hand-roll (T12/m240)
static __device__ __forceinline__ u16 f2b(float f) {
  return __builtin_bit_cast(u16, (__bf16)f);
}
static __device__ __forceinline__ float b2f(u16 h) {
  union { unsigned u; float f; } v; v.u = ((unsigned)h) << 16;
  return v.f;
}
static __device__ __forceinline__ f32x4 mfma_bf16(short8 a, short8 b, f32x4 c) {
  return __builtin_amdgcn_mfma_f32_16x16x32_bf16(
      __builtin_bit_cast(bf16x8, a), __builtin_bit_cast(bf16x8, b), c, 0, 0, 0);
}
// async global->LDS, 16B per lane; lds ptr must be wave-uniform base (HW adds lane*16)
static __device__ __forceinline__ void gload_lds16(const u16* g, u16* l) {
  __builtin_amdgcn_global_load_lds(
      (const __attribute__((address_space(1))) unsigned int*)g,
      (__attribute__((address_space(3))) unsigned int*)l, 16, 0, 0);
}

// ---------- problem constants ----------
#define BB 2
#define TT 2048
#define DD 2048
#define NH 16
#define NKVH 4
#define HD 128
#define MM (BB * TT)          // 4096 rows
#define QSTR 3072             // fused QKV projection row: [Q(2048) | K(512) | V(512)]
#define QSCALE 0.08838834764831845f

// ---------- fp32 -> bf16 convert, WEIGHTS ONLY (x is converted inside gemm_qkv) ----------
#define N4_WQ  ((DD * DD) / 4)
#define N4_WKV ((NKVH * HD * DD) / 4)
#define N4_WO  ((DD * DD) / 4)
#define N4W_TOT (N4_WQ + 2 * N4_WKV + N4_WO)

__global__ __launch_bounds__(256) void cvt_w(const float* __restrict__ wq,
                                             const float* __restrict__ wk,
                                             const float* __restrict__ wv,
                                             const float* __restrict__ wo,
                                             u16* __restrict__ wqkvb,
                                             u16* __restrict__ wob) {
  int stride = gridDim.x * blockDim.x;
  for (int i = blockIdx.x * blockDim.x + threadIdx.x; i < N4W_TOT; i += stride) {
    const float4v* src;
    u16x4* dst;
    int off;
    if (i < N4_WQ) {
      src = (const float4v*)wq; dst = (u16x4*)wqkvb; off = i;
    } else if (i < N4_WQ + N4_WKV) {
      src = (const float4v*)wk; dst = (u16x4*)wqkvb + N4_WQ; off = i - N4_WQ;
    } else if (i < N4_WQ + 2 * N4_WKV) {
      src = (const float4v*)wv; dst = (u16x4*)wqkvb + N4_WQ + N4_WKV;
      off = i - (N4_WQ + N4_WKV);
    } else {
      src = (const float4v*)wo; dst = (u16x4*)wob; off = i - (N4_WQ + 2 * N4_WKV);
    }
    float4v v = src[off];
    u16x4 o;
    o[0] = f2b(v[0]); o[1] = f2b(v[1]); o[2] = f2b(v[2]); o[3] = f2b(v[3]);
    dst[off] = o;
  }
}

// ---------- RoPE on K only (Q-rope is fused into the attention prologue) ----------
__global__ __launch_bounds__(256) void rope_k(u16* __restrict__ K,
                                              const float* __restrict__ rope) {
  int idx = blockIdx.x * 256 + threadIdx.x;
  int i  = idx & 63;
  int h  = (idx >> 6) & (NKVH - 1);
  int bt = idx >> 8;
  int t  = bt & (TT - 1);
  size_t base = (size_t)bt * QSTR + h * HD + i;
  float x1 = b2f(K[base]);
  float x2 = b2f(K[base + 64]);
  float c = rope[t * 128 + 2 * i];
  float s = rope[t * 128 + 2 * i + 1];
  K[base]      = f2b(x1 * c - x2 * s);
  K[base + 64] = f2b(x1 * s + x2 * c);
}

// ---------- 256x192 counted-vmcnt GEMM (QKV projection, bf16 out) ----------
// NEW: A (= x) is read as fp32 and converted in-register during staging,
// eliminating the xb round-trip (33.6 MB HBM). The LDS image is byte-identical
// to the gload_lds one (per-thread ds_write_b128 at lane*16B), read side
// unchanged. Counted-vmcnt ledger: per iter, issue A-regs (8, OLDEST) then
// W-gloads (3, NEWEST); vmcnt(11) at tile top drains exactly W(t);
// after B2, vmcnt(3) drains A(t+1) regs while W(t+1) stays in flight;
// write-late (T14) into the idle buffer; lgkmcnt(0) before B1 makes the
// A-writes cross-wave visible.
__global__ __launch_bounds__(512) void gemm_qkv(const float* __restrict__ X,
                                                const u16* __restrict__ W,
                                                u16* __restrict__ C,
                                                int M, int N, int K) {
  __shared__ __align__(16) u16 As[2][2][128 * 64];  // [buf][half][r*64+swz] 64KB
  __shared__ __align__(16) u16 Ws[2][192 * 64];     // [buf][r*64+swz]       48KB

  const int tid = threadIdx.x, lane = tid & 63, wid = tid >> 6;
  const int wm = wid >> 2, wn = wid & 3;
  const int l15 = lane & 15, lh = lane >> 4;

  // T1 bijective XCD swizzle (nwg = 256, %8 == 0)
  const int nwg = gridDim.x * gridDim.y;
  const int lin = blockIdx.y * gridDim.x + blockIdx.x;
  const int swz = (lin & 7) * (nwg >> 3) + (lin >> 3);
  const int brow = (swz / gridDim.x) * 256, bcol = (swz % gridDim.x) * 192;

  const int srp = wid * 8 + (lane >> 3);
  const int gsw = ((lane & 7) ^ (lane >> 3)) << 3;
  const float* xa[2][2];
  const u16* sw3[3];
#pragma unroll
  for (int mh = 0; mh < 2; ++mh)
#pragma unroll
    for (int i = 0; i < 2; ++i)
      xa[mh][i] = X + (size_t)(brow + mh * 128 + i * 64 + srp) * K + gsw;
#pragma unroll
  for (int i = 0; i < 3; ++i)
    sw3[i] = W + (size_t)(bcol + i * 64 + srp) * K + gsw;

  f32x4 acc[8][3];
#pragma unroll
  for (int mi = 0; mi < 8; ++mi)
#pragma unroll
    for (int ni = 0; ni < 3; ++ni) acc[mi][ni] = (f32x4)0.0f;

  const int nk = K >> 6;  // 64-wide K tiles

  float4v areg[4][2];     // staged A fp32 (T14: load early, write late)
  auto loadA = [&](int t) {
#pragma unroll
    for (int mh = 0; mh < 2; ++mh)
#pragma unroll
      for (int i = 0; i < 2; ++i) {
        const float* s = xa[mh][i] + t * 64;
        areg[mh * 2 + i][0] = *(const float4v*)(s);
        areg[mh * 2 + i][1] = *(const float4v*)(s + 4);
      }
  };
  auto writeA = [&](int p) {
#pragma unroll
    for (int mh = 0; mh < 2; ++mh)
#pragma unroll
      for (int i = 0; i < 2; ++i) {
        short8 o;
#pragma unroll
        for (int e = 0; e < 4; ++e) {
          o[e]     = (short)f2b(areg[mh * 2 + i][0][e]);
          o[4 + e] = (short)f2b(areg[mh * 2 + i][1][e]);
        }
        *(short8*)&As[p][mh][i * 4096 + wid * 512 + lane * 8] = o;
      }
  };
  auto issueW = [&](int t, int p) {
#pragma unroll
    for (int i = 0; i < 3; ++i)
      gload_lds16(sw3[i] + t * 64, &Ws[p][i * 4096 + wid * 512]);
  };

  // prologue: tile 0 into buf 0 (A regs drained with vmcnt(3); W(0) stays)
  loadA(0);
  issueW(0, 0);
  asm volatile("s_waitcnt vmcnt(3)" ::: "memory");
  writeA(0);

  for (int t = 0; t < nk; ++t) {
    const int p = t & 1;
    if (t + 1 < nk) {
      loadA(t + 1);         // 8 vmem, oldest of this iteration's issues
      issueW(t + 1, p ^ 1); // 3 gload_lds, newest
      asm volatile("s_waitcnt vmcnt(11)" ::: "memory");  // drains W(t)
    } else {
      asm volatile("s_waitcnt vmcnt(0)" ::: "memory");
    }
    asm volatile("s_waitcnt lgkmcnt(0)" ::: "memory");   // my A(t) writes done
    __builtin_amdgcn_sched_barrier(0);
    __builtin_amdgcn_s_barrier();   // B1: all waves' tile-t stages visible
    __builtin_amdgcn_sched_barrier(0);

    const u16* Ab = &As[p][wm][0];
    const u16* Wb = &Ws[p][0];

    short8 af[4][2], bf[3][2];
    // B frags (cols wn*48 + {0,16,32}), reused across both phases
#pragma unroll
    for (int ni = 0; ni < 3; ++ni)
#pragma unroll
      for (int ks = 0; ks < 2; ++ks) {
        int rh = wn * 48 + ni * 16 + l15;
        bf[ni][ks] = *(const short8*)&Wb[rh * 64 + (((ks * 4 + lh) ^ (rh & 7)) << 3)];
      }
    // ---- phase 0: A lo half
#pragma unroll
    for (int mi = 0; mi < 4; ++mi)
#pragma unroll
      for (int ks = 0; ks < 2; ++ks) {
        int rh = mi * 16 + l15;
        af[mi][ks] = *(const short8*)&Ab[rh * 64 + (((ks * 4 + lh) ^ (rh & 7)) << 3)];
      }
    __builtin_amdgcn_s_setprio(1);
#pragma unroll
    for (int mi = 0; mi < 4; ++mi)
#pragma unroll
      for (int ni = 0; ni < 3; ++ni)
#pragma unroll
        for (int ks = 0; ks < 2; ++ks)
          acc[mi][ni] = mfma_bf16(af[mi][ks], bf[ni][ks], acc[mi][ni]);
    __builtin_amdgcn_s_setprio(0);
    // (mid-phase barrier removed: phase-1 ds_reads pipeline under phase-0 MFMA)
    // ---- phase 1: A hi half
#pragma unroll
    for (int mi = 0; mi < 4; ++mi)
#pragma unroll
      for (int ks = 0; ks < 2; ++ks) {
        int rh = (4 + mi) * 16 + l15;
        af[mi][ks] = *(const short8*)&Ab[rh * 64 + (((ks * 4 + lh) ^ (rh & 7)) << 3)];
      }
    __builtin_amdgcn_s_setprio(1);
#pragma unroll
    for (int mi = 0; mi < 4; ++mi)
#pragma unroll
      for (int ni = 0; ni < 3; ++ni)
#pragma unroll
        for (int ks = 0; ks < 2; ++ks)
          acc[4 + mi][ni] = mfma_bf16(af[mi][ks], bf[ni][ks], acc[4 + mi][ni]);
    __builtin_amdgcn_s_setprio(0);

    // B2: all reads of buf[p] complete before the next writes overwrite it
    asm volatile("s_waitcnt lgkmcnt(0)" ::: "memory");
    __builtin_amdgcn_sched_barrier(0);
    __builtin_amdgcn_s_barrier();
    __builtin_amdgcn_sched_barrier(0);
    if (t + 1 < nk) {
      asm volatile("s_waitcnt vmcnt(3)" ::: "memory");  // A(t+1) regs ready; W(t+1) stays
      writeA(p ^ 1);   // write-late into the idle buffer (visible by next B1)
    }
  }

  // ---- epilogue (bf16)
#pragma unroll
  for (int mi = 0; mi < 8; ++mi)
#pragma unroll
    for (int ni = 0; ni < 3; ++ni)
#pragma unroll
      for (int j = 0; j < 4; ++j) {
        int row = brow + wm * 128 + mi * 16 + lh * 4 + j;
        int col = bcol + wn * 48 + ni * 16 + l15;
        C[(size_t)row * N + col] = f2b(acc[mi][ni][j]);
      }
}

// ---------- 256x128 counted-vmcnt GEMM (WO projection, fp32 out) ----------
// Mid-phase barrier removed (no correctness role; B1 + B2 protect buffers).
__global__ __launch_bounds__(512, 2) void gemm_wo(const u16* __restrict__ A,
                                                  const u16* __restrict__ W,
                                                  float* __restrict__ C,
                                                  int M, int N, int K) {
  __shared__ __align__(16) u16 As[2][2][128 * 64];  // [buf][half][r*64+swz] 64KB
  __shared__ __align__(16) u16 Ws[2][128 * 64];     // [buf][r*64+swz]       32KB

  const int tid = threadIdx.x, lane = tid & 63, wid = tid >> 6;
  const int wm = wid >> 2, wn = wid & 3;
  const int l15 = lane & 15, lh = lane >> 4;

  // T1 bijective XCD swizzle (nwg = 256, %8 == 0)
  const int nwg = gridDim.x * gridDim.y;
  const int lin = blockIdx.y * gridDim.x + blockIdx.x;
  const int swz = (lin & 7) * (nwg >> 3) + (lin >> 3);
  const int brow = (swz / gridDim.x) * 256, bcol = (swz % gridDim.x) * 128;

  const int srp = wid * 8 + (lane >> 3);
  const int gsw = ((lane & 7) ^ (lane >> 3)) << 3;
  const u16* sa[2][2];
  const u16* sw2[2];
#pragma unroll
  for (int mh = 0; mh < 2; ++mh)
#pragma unroll
    for (int i = 0; i < 2; ++i)
      sa[mh][i] = A + (size_t)(brow + mh * 128 + i * 64 + srp) * K + gsw;
#pragma unroll
  for (int i = 0; i < 2; ++i)
    sw2[i] = W + (size_t)(bcol + i * 64 + srp) * K + gsw;

  f32x4 acc[8][2];
#pragma unroll
  for (int mi = 0; mi < 8; ++mi)
#pragma unroll
    for (int ni = 0; ni < 2; ++ni) acc[mi][ni] = (f32x4)0.0f;

  const int nk = K >> 6;

  auto issue = [&](int t, int p) {
#pragma unroll
    for (int mh = 0; mh < 2; ++mh)
#pragma unroll
      for (int i = 0; i < 2; ++i)
        gload_lds16(sa[mh][i] + t * 64, &As[p][mh][i * 4096 + wid * 512]);
#pragma unroll
    for (int i = 0; i < 2; ++i)
      gload_lds16(sw2[i] + t * 64, &Ws[p][i * 4096 + wid * 512]);
  };

  issue(0, 0);
  for (int t = 0; t < nk; ++t) {
    const int p = t & 1;
    if (t + 1 < nk) {
      issue(t + 1, p ^ 1);  // 6 loads for tile t+1 stay in flight
      asm volatile("s_waitcnt vmcnt(6)" ::: "memory");  // tile t's 6 landed
    } else {
      asm volatile("s_waitcnt vmcnt(0)" ::: "memory");
    }
    __builtin_amdgcn_sched_barrier(0);
    __builtin_amdgcn_s_barrier();   // B1: tile-t stages visible
    __builtin_amdgcn_sched_barrier(0);

    const u16* Ab = &As[p][wm][0];
    const u16* Wb = &Ws[p][0];

    short8 af[4][2], bf[2][2];
    // B frags (cols wn*32 + {0,16}), reused across both phases
#pragma unroll
    for (int ni = 0; ni < 2; ++ni)
#pragma unroll
      for (int ks = 0; ks < 2; ++ks) {
        int rh = wn * 32 + ni * 16 + l15;
        bf[ni][ks] = *(const short8*)&Wb[rh * 64 + (((ks * 4 + lh) ^ (rh & 7)) << 3)];
      }
    // ---- phase 0: A lo half
#pragma unroll
    for (int mi = 0; mi < 4; ++mi)
#pragma unroll
      for (int ks = 0; ks < 2; ++ks) {
        int rh = mi * 16 + l15;
        af[mi][ks] = *(const short8*)&Ab[rh * 64 + (((ks * 4 + lh) ^ (rh & 7)) << 3)];
      }
    __builtin_amdgcn_s_setprio(1);
#pragma unroll
    for (int mi = 0; mi < 4; ++mi)
#pragma unroll
      for (int ni = 0; ni < 2; ++ni)
#pragma unroll
        for (int ks = 0; ks < 2; ++ks)
          acc[mi][ni] = mfma_bf16(af[mi][ks], bf[ni][ks], acc[mi][ni]);
    __builtin_amdgcn_s_setprio(0);
    // (mid-phase barrier removed)
    // ---- phase 1: A hi half
#pragma unroll
    for (int mi = 0; mi < 4; ++mi)
#pragma unroll
      for (int ks = 0; ks < 2; ++ks) {
        int rh = (4 + mi) * 16 + l15;
        af[mi][ks] = *(const short8*)&Ab[rh * 64 + (((ks * 4 + lh) ^ (rh & 7)) << 3)];
      }
    __builtin_amdgcn_s_setprio(1);
#pragma unroll
    for (int mi = 0; mi < 4; ++mi)
#pragma unroll
      for (int ni = 0; ni < 2; ++ni)
#pragma unroll
        for (int ks = 0; ks < 2; ++ks)
          acc[4 + mi][ni] = mfma_bf16(af[mi][ks], bf[ni][ks], acc[4 + mi][ni]);
    __builtin_amdgcn_s_setprio(0);

    // B2: all reads of buf[p] complete before iter t+2's issue overwrites it
    asm volatile("s_waitcnt lgkmcnt(0)" ::: "memory");
    __builtin_amdgcn_sched_barrier(0);
    __builtin_amdgcn_s_barrier();
    __builtin_amdgcn_sched_barrier(0);
  }

  // ---- epilogue (fp32)
#pragma unroll
  for (int mi = 0; mi < 8; ++mi)
#pragma unroll
    for (int ni = 0; ni < 2; ++ni)
#pragma unroll
      for (int j = 0; j < 4; ++j) {
        int row = brow + wm * 128 + mi * 16 + lh * 4 + j;
        int col = bcol + wn * 32 + ni * 16 + l15;
        C[(size_t)row * N + col] = acc[mi][ni][j];
      }
}

// ---------- fused causal GQA flash attention (best measured: 91.2 µs) ----------
// 256 blocks x 8 waves (512 thr), complementary q-tile pairing (qp, 15-qp)
// — optimal: pairs the max-work stream with the min-work stream so the
// makespan block's SIMDs are not oversubscribed (R14 lesson). Swapped QK^T
// softmax, T14 reg-staging (two barriers/tile — both cheaper variants
// measured worse: R0-style x2-calls and R16 dbuf/gload_lds), KVBLK=128.
#define QBLK 128
#define KVBLK 128

static __device__ __forceinline__ void attn_tile(
    const short8* qa, f32x4* o, float& l, float& m,
    int qrow0, int kv0,
    const u16* Ks, const unsigned* Vt32, u16* myP,
    int l15, int lh) {
  if (kv0 > qrow0 + 15) return;   // fully masked for this wave

  // ---- swapped QK^T: st[nt][j] = S[kv = kv0+nt*16+lh*4+j][q = qrow0+l15]
  f32x4 st[4];
#pragma unroll
  for (int nt = 0; nt < 4; ++nt) st[nt] = (f32x4)0.0f;
  __builtin_amdgcn_s_setprio(1);
#pragma unroll
  for (int nt = 0; nt < 4; ++nt) {
    const u16* krow = &Ks[(nt * 16 + l15) * 136 + (lh << 3)];
#pragma unroll
    for (int kk = 0; kk < 4; ++kk) {
      short8 kb = *(const short8*)(krow + kk * 32);
      st[nt] = mfma_bf16(kb, qa[kk], st[nt]);
    }
  }
  __builtin_amdgcn_s_setprio(0);

  // ---- causal mask: kv > q  <=>  (kv0 + lh*4 - qrow0 - l15) + nt*16 + j > 0
  const int kvq = kv0 + lh * 4 - qrow0 - l15;
#pragma unroll
  for (int nt = 0; nt < 4; ++nt)
#pragma unroll
    for (int j = 0; j < 4; ++j)
      if (kvq + nt * 16 + j > 0) st[nt][j] = -1e30f;

  // ---- in-lane row max (q = l15), then reduce across the 4 lh groups
  float mt = st[0][0];
#pragma unroll
  for (int nt = 0; nt < 4; ++nt)
#pragma unroll
    for (int j = 0; j < 4; ++j) mt = fmaxf(mt, st[nt][j]);
  mt = fmaxf(mt, __shfl_xor(mt, 16));
  mt = fmaxf(mt, __shfl_xor(mt, 32));

  // ---- defer-max (T13): rescale only when max grew by > 8
  if (!__all(mt - m <= 8.0f)) {
    float mn = fmaxf(m, mt);
    float a = __expf(m - mn);
    m = mn;
    l *= a;
    float aj[4];
#pragma unroll
    for (int j = 0; j < 4; ++j) aj[j] = __shfl(a, lh * 4 + j);
#pragma unroll
    for (int n = 0; n < 8; ++n)
#pragma unroll
      for (int j = 0; j < 4; ++j) o[n][j] *= aj[j];
  }

  // ---- P = exp(S - m); row-sum accumulated in-lane (partial over this lh)
  f32x4 p[4];
  float ps = 0.0f;
#pragma unroll
  for (int nt = 0; nt < 4; ++nt) {
#pragma unroll
    for (int j = 0; j < 4; ++j) p[nt][j] = __expf(st[nt][j] - m);
    ps += (p[nt][0] + p[nt][1]) + (p[nt][2] + p[nt][3]);
  }
  l += ps;

  // ---- P -> per-wave LDS, pair-packed b32 at elem l15*72 + kv
  unsigned* P32 = (unsigned*)myP;
  const int pb = l15 * 36 + lh * 2;
#pragma unroll
  for (int nt = 0; nt < 4; ++nt)
#pragma unroll
    for (int jj = 0; jj < 2; ++jj)
      P32[pb + nt * 8 + jj] =
          (unsigned)f2b(p[nt][2 * jj]) | ((unsigned)f2b(p[nt][2 * jj + 1]) << 16);

  // ---- PV (read pattern unchanged from verified kernel)
  __builtin_amdgcn_s_setprio(1);
#pragma unroll
  for (int c = 0; c < 2; ++c) {
    short8 pa = *(const short8*)&myP[l15 * 72 + c * 32 + (lh << 3)];
#pragma unroll
    for (int nt2 = 0; nt2 < 8; ++nt2) {
      int d = nt2 * 16 + l15;
      int byteoff = (d * 144 + (c * 32 + lh * 8) * 2) ^ (((d >> 3) & 7) << 4);
      short8 vb = *(const short8*)((const char*)Vt32 + byteoff);
      o[nt2] = mfma_bf16(pa, vb, o[nt2]);
    }
  }
  __builtin_amdgcn_s_setprio(0);
}

__global__ __launch_bounds__(512) void attn_kernel(const u16* __restrict__ QKV,
                                                   const float* __restrict__ rope,
                                                   u16* __restrict__ Y) {
  __shared__ __align__(16) u16 Ks[2][64 * 136];        // 2 x 17408 B
  __shared__ __align__(16) unsigned Vt32[2][128 * 36]; // 2 x 18432 B
  __shared__ __align__(16) u16 Ps[8][16 * 72];         // 18432 B

  const int tid = threadIdx.x, lane = tid & 63, wid = tid >> 6;
  const int l15 = lane & 15, lh = lane >> 4;
  const int bid = blockIdx.x;
  const int qpair = bid & 7;
  const int h = (bid >> 3) & 15;
  const int b = bid >> 7;
  const int kvh = h >> 2;
  const int qtA = qpair, qtB = 15 - qpair;
  const int rowA = qtA * QBLK + wid * 16;
  const int rowB = qtB * QBLK + wid * 16;

  const u16* Kb_ = QKV + (size_t)b * TT * QSTR + DD + kvh * HD;  // K cols
  const u16* Vb_ = Kb_ + NKVH * HD;                              // V cols

  short8 qaA[4], qaB[4];
  {
    const u16* qA = QKV + (size_t)(b * TT + rowA + l15) * QSTR + h * HD + (lh << 3);
    const u16* qB = QKV + (size_t)(b * TT + rowB + l15) * QSTR + h * HD + (lh << 3);
#pragma unroll
    for (int kk = 0; kk < 4; ++kk) {
      qaA[kk] = *(const short8*)(qA + kk * 32);
      qaB[kk] = *(const short8*)(qB + kk * 32);
    }
  }
  // ---- fused Q-RoPE + softmax scale (pair (i, i+64) = qa[kk] / qa[kk+2])
  {
    const float* rpA = rope + (size_t)(rowA + l15) * 128;
    const float* rpB = rope + (size_t)(rowB + l15) * 128;
#pragma unroll
    for (int kk = 0; kk < 2; ++kk)
#pragma unroll
      for (int e = 0; e < 8; ++e) {
        const int i2 = 2 * (kk * 32 + (lh << 3) + e);
        float c = rpA[i2], s = rpA[i2 + 1];
        float x1 = b2f((u16)qaA[kk][e]), x2 = b2f((u16)qaA[kk + 2][e]);
        qaA[kk][e]     = (short)f2b(QSCALE * (x1 * c - x2 * s));
        qaA[kk + 2][e] = (short)f2b(QSCALE * (x1 * s + x2 * c));
        float cb = rpB[i2], sb = rpB[i2 + 1];
        float y1 = b2f((u16)qaB[kk][e]), y2 = b2f((u16)qaB[kk + 2][e]);
        qaB[kk][e]     = (short)f2b(QSCALE * (y1 * cb - y2 * sb));
        qaB[kk + 2][e] = (short)f2b(QSCALE * (y1 * sb + y2 * cb));
      }
  }

  f32x4 oA[8], oB[8];
  float lA = 0.0f, lB = 0.0f;
  float mA = -1e30f, mB = -1e30f;
#pragma unroll
  for (int n = 0; n < 8; ++n) { oA[n] = (f32x4)0.0f; oB[n] = (f32x4)0.0f; }

  const int kvend = (qtB + 1) * QBLK;   // multiple of 128

  // staging registers (T14: issue early, write late); 128 KV rows per pass
  short8 kreg[4], vreg[4];
  const int srow = tid >> 4;           // 0..31
  const int sc8 = (tid & 15) << 3;

  auto issue = [&](int kv0) {
    kreg[0] = *(const short8*)&Kb_[(size_t)(kv0 + srow) * QSTR + sc8];
    kreg[1] = *(const short8*)&Kb_[(size_t)(kv0 + 32 + srow) * QSTR + sc8];
    kreg[2] = *(const short8*)&Kb_[(size_t)(kv0 + 64 + srow) * QSTR + sc8];
    kreg[3] = *(const short8*)&Kb_[(size_t)(kv0 + 96 + srow) * QSTR + sc8];
    vreg[0] = *(const short8*)&Vb_[(size_t)(kv0 + 2 * srow) * QSTR + sc8];
    vreg[1] = *(const short8*)&Vb_[(size_t)(kv0 + 2 * srow + 1) * QSTR + sc8];
    vreg[2] = *(const short8*)&Vb_[(size_t)(kv0 + 64 + 2 * srow) * QSTR + sc8];
    vreg[3] = *(const short8*)&Vb_[(size_t)(kv0 + 64 + 2 * srow + 1) * QSTR + sc8];
  };

  issue(0);
  for (int kv0 = 0; kv0 < kvend; kv0 += KVBLK) {
    __syncthreads();   // previous tile's LDS reads done
    *(short8*)&Ks[0][srow * 136 + sc8] = kreg[0];
    *(short8*)&Ks[0][(srow + 32) * 136 + sc8] = kreg[1];
    *(short8*)&Ks[1][srow * 136 + sc8] = kreg[2];
    *(short8*)&Ks[1][(srow + 32) * 136 + sc8] = kreg[3];
#pragma unroll
    for (int e = 0; e < 8; ++e) {
      int d = sc8 + e;
      unsigned pk0 = (unsigned)(u16)vreg[0][e] | ((unsigned)(u16)vreg[1][e] << 16);
      unsigned pk1 = (unsigned)(u16)vreg[2][e] | ((unsigned)(u16)vreg[3][e] << 16);
      int byteoff = (d * 144 + 4 * srow) ^ (((d >> 3) & 7) << 4);
      *(unsigned*)((char*)&Vt32[0][0] + byteoff) = pk0;
      *(unsigned*)((char*)&Vt32[1][0] + byteoff) = pk1;
    }
    __syncthreads();   // staged tile visible
    if (kv0 + KVBLK < kvend) issue(kv0 + KVBLK);  // overlap next loads with compute

    attn_tile(qaA, oA, lA, mA, rowA, kv0,      &Ks[0][0], &Vt32[0][0], &Ps[wid][0], l15, lh);
    attn_tile(qaA, oA, lA, mA, rowA, kv0 + 64, &Ks[1][0], &Vt32[1][0], &Ps[wid][0], l15, lh);
    attn_tile(qaB, oB, lB, mB, rowB, kv0,      &Ks[0][0], &Vt32[0][0], &Ps[wid][0], l15, lh);
    attn_tile(qaB, oB, lB, mB, rowB, kv0 + 64, &Ks[1][0], &Vt32[1][0], &Ps[wid][0], l15, lh);
  }

  // ---- epilogue: total row-sums (reduce over lh), redistribute to q=lh*4+j
  lA += __shfl_xor(lA, 16); lA += __shfl_xor(lA, 32);
  lB += __shfl_xor(lB, 16); lB += __shfl_xor(lB, 32);
  f32x4 invA, invB;
#pragma unroll
  for (int j = 0; j < 4; ++j) {
    invA[j] = __builtin_amdgcn_rcpf(__shfl(lA, lh * 4 + j));
    invB[j] = __builtin_amdgcn_rcpf(__shfl(lB, lh * 4 + j));
  }
#pragma unroll
  for (int nt = 0; nt < 8; ++nt)
#pragma unroll
    for (int j = 0; j < 4; ++j) {
      Y[(size_t)(b * TT + rowA + lh * 4 + j) * DD + h * HD + nt * 16 + l15] =
          f2b(oA[nt][j] * invA[j]);
      Y[(size_t)(b * TT + rowB + lh * 4 + j) * DD + h * HD + nt * 16 + l15] =
          f2b(oB[nt][j] * invB[j]);
    }
}

// ---------- launcher ----------
extern "C" void kernel_launch(void* const* d_in, const int* in_sizes, int n_in,
                              void* d_out, int out_size, void* d_ws, size_t ws_size,
                              hipStream_t stream) {
  const float* x    = (const float*)d_in[0];
  const float* rope = (const float*)d_in[1];
  const float* wq   = (const float*)d_in[2];
  const float* wk   = (const float*)d_in[3];
  const float* wv   = (const float*)d_in[4];
  const float* wo   = (const float*)d_in[5];
  float* out = (float*)d_out;

  char* ws = (char*)d_ws;
  u16* wqkvb = (u16*)ws; ws += (size_t)QSTR * DD * 2;      // 12.6 MB (wq|wk|wv rows)
  u16* wob   = (u16*)ws; ws += (size_t)DD * DD * 2;        //  8.4 MB
  u16* QKVb  = (u16*)ws; ws += (size_t)MM * QSTR * 2;      // 25.2 MB
  u16* Yb    = (u16*)ws;                                   // 16.8 MB

  // 1) weight converts only (x is converted inside gemm_qkv's A staging)
  cvt_w<<<2048, 256, 0, stream>>>(wq, wk, wv, wo, wqkvb, wob);

  // 2) fused QKV projection: 256x192 counted-vmcnt GEMM, fp32 A in-staging cvt
  gemm_qkv<<<dim3(QSTR / 192, MM / 256), 512, 0, stream>>>(x, wqkvb, QKVb, MM, QSTR, DD);

  // 3) RoPE on K only (Q-rope fused into attention)
  rope_k<<<(MM * NKVH * 64) / 256, 256, 0, stream>>>(QKVb + DD, rope);

  // 4) attention (best measured: complementary pairing, 512 threads)
  attn_kernel<<<BB * NH * (TT / QBLK / 2), 512, 0, stream>>>(QKVb, rope, Yb);

  // 5) output projection: 256x128 counted-vmcnt GEMM (256 blocks, 1/CU)
  gemm_wo<<<dim3(DD / 128, MM / 256), 512, 0, stream>>>(Yb, wob, out, MM, DD, DD);
}

// Round 19
// 198.170 us; speedup vs baseline: 1.0238x; 1.0238x over previous
//
#include <hip/hip_runtime.h>

// ---------- types & helpers ----------
typedef unsigned short u16;
typedef float   f32x4  __attribute__((ext_vector_type(4)));
typedef short   short8 __attribute__((ext_vector_type(8)));
typedef __bf16  bf16x8 __attribute__((ext_vector_type(8)));
typedef float   float4v __attribute__((ext_vector_type(4)));
typedef unsigned short u16x4 __attribute__((ext_vector_type(4)));

// native HW bf16 convert (RNE) — do not hand-roll (T12/m240)
static __device__ __forceinline__ u16 f2b(float f) {
  return __builtin_bit_cast(u16, (__bf16)f);
}
static __device__ __forceinline__ float b2f(u16 h) {
  union { unsigned u; float f; } v; v.u = ((unsigned)h) << 16;
  return v.f;
}
static __device__ __forceinline__ f32x4 mfma_bf16(short8 a, short8 b, f32x4 c) {
  return __builtin_amdgcn_mfma_f32_16x16x32_bf16(
      __builtin_bit_cast(bf16x8, a), __builtin_bit_cast(bf16x8, b), c, 0, 0, 0);
}
// async global->LDS, 16B per lane; lds ptr must be wave-uniform base (HW adds lane*16)
static __device__ __forceinline__ void gload_lds16(const u16* g, u16* l) {
  __builtin_amdgcn_global_load_lds(
      (const __attribute__((address_space(1))) unsigned int*)g,
      (__attribute__((address_space(3))) unsigned int*)l, 16, 0, 0);
}

// ---------- problem constants ----------
#define BB 2
#define TT 2048
#define DD 2048
#define NH 16
#define NKVH 4
#define HD 128
#define MM (BB * TT)          // 4096 rows
#define QSTR 3072             // fused QKV projection row: [Q(2048) | K(512) | V(512)]
#define QSCALE 0.08838834764831845f

// ---------- fused fp32 -> bf16 convert (all 5 tensors, 1 launch) ----------
// NOTE (R18 lesson): converting x here and re-reading xb in gemm_qkv is
// nearly free — xb is L3-resident when gemm_qkv runs. Fusing the convert
// into the GEMM replaced warm bf16 reads with cold fp32 reads (2x bytes,
// 1.6x refetch) and cost +55 µs. Keep the round-trip.
#define N4_X   ((MM * DD) / 4)
#define N4_WQ  ((DD * DD) / 4)
#define N4_WKV ((NKVH * HD * DD) / 4)
#define N4_WO  ((DD * DD) / 4)
#define N4_TOT (N4_X + N4_WQ + 2 * N4_WKV + N4_WO)

__global__ __launch_bounds__(256) void cvt_all(const float* __restrict__ x,
                                               const float* __restrict__ wq,
                                               const float* __restrict__ wk,
                                               const float* __restrict__ wv,
                                               const float* __restrict__ wo,
                                               u16* __restrict__ xb,
                                               u16* __restrict__ wqkvb,
                                               u16* __restrict__ wob) {
  int stride = gridDim.x * blockDim.x;
  for (int i = blockIdx.x * blockDim.x + threadIdx.x; i < N4_TOT; i += stride) {
    const float4v* src;
    u16x4* dst;
    int off;
    if (i < N4_X) {
      src = (const float4v*)x; dst = (u16x4*)xb; off = i;
    } else if (i < N4_X + N4_WQ) {
      src = (const float4v*)wq; dst = (u16x4*)wqkvb; off = i - N4_X;
    } else if (i < N4_X + N4_WQ + N4_WKV) {
      src = (const float4v*)wk; dst = (u16x4*)wqkvb + N4_WQ; off = i - (N4_X + N4_WQ);
    } else if (i < N4_X + N4_WQ + 2 * N4_WKV) {
      src = (const float4v*)wv; dst = (u16x4*)wqkvb + N4_WQ + N4_WKV;
      off = i - (N4_X + N4_WQ + N4_WKV);
    } else {
      src = (const float4v*)wo; dst = (u16x4*)wob; off = i - (N4_X + N4_WQ + 2 * N4_WKV);
    }
    float4v v = src[off];
    u16x4 o;
    o[0] = f2b(v[0]); o[1] = f2b(v[1]); o[2] = f2b(v[2]); o[3] = f2b(v[3]);
    dst[off] = o;
  }
}

// ---------- RoPE on K only (Q-rope is fused into the attention prologue) ----------
__global__ __launch_bounds__(256) void rope_k(u16* __restrict__ K,
                                              const float* __restrict__ rope) {
  int idx = blockIdx.x * 256 + threadIdx.x;
  int i  = idx & 63;
  int h  = (idx >> 6) & (NKVH - 1);
  int bt = idx >> 8;
  int t  = bt & (TT - 1);
  size_t base = (size_t)bt * QSTR + h * HD + i;
  float x1 = b2f(K[base]);
  float x2 = b2f(K[base + 64]);
  float c = rope[t * 128 + 2 * i];
  float s = rope[t * 128 + 2 * i + 1];
  K[base]      = f2b(x1 * c - x2 * s);
  K[base + 64] = f2b(x1 * s + x2 * c);
}

// ---------- 256x192 counted-vmcnt GEMM (QKV projection, bf16 out) ----------
// Mid-phase barrier removed (no correctness role; B1 + B2 protect buffers) so
// phase-1's ds_reads pipeline under phase-0's MFMA.
__global__ __launch_bounds__(512) void gemm_qkv(const u16* __restrict__ A,
                                                const u16* __restrict__ W,
                                                u16* __restrict__ C,
                                                int M, int N, int K) {
  __shared__ __align__(16) u16 As[2][2][128 * 64];  // [buf][half][r*64+swz] 64KB
  __shared__ __align__(16) u16 Ws[2][192 * 64];     // [buf][r*64+swz]       48KB

  const int tid = threadIdx.x, lane = tid & 63, wid = tid >> 6;
  const int wm = wid >> 2, wn = wid & 3;
  const int l15 = lane & 15, lh = lane >> 4;

  // T1 bijective XCD swizzle (nwg = 256, %8 == 0)
  const int nwg = gridDim.x * gridDim.y;
  const int lin = blockIdx.y * gridDim.x + blockIdx.x;
  const int swz = (lin & 7) * (nwg >> 3) + (lin >> 3);
  const int brow = (swz / gridDim.x) * 256, bcol = (swz % gridDim.x) * 192;

  const int srp = wid * 8 + (lane >> 3);
  const int gsw = ((lane & 7) ^ (lane >> 3)) << 3;
  const u16* sa[2][2];
  const u16* sw3[3];
#pragma unroll
  for (int mh = 0; mh < 2; ++mh)
#pragma unroll
    for (int i = 0; i < 2; ++i)
      sa[mh][i] = A + (size_t)(brow + mh * 128 + i * 64 + srp) * K + gsw;
#pragma unroll
  for (int i = 0; i < 3; ++i)
    sw3[i] = W + (size_t)(bcol + i * 64 + srp) * K + gsw;

  f32x4 acc[8][3];
#pragma unroll
  for (int mi = 0; mi < 8; ++mi)
#pragma unroll
    for (int ni = 0; ni < 3; ++ni) acc[mi][ni] = (f32x4)0.0f;

  const int nk = K >> 6;  // 64-wide K tiles

  auto issue = [&](int t, int p) {
#pragma unroll
    for (int mh = 0; mh < 2; ++mh)
#pragma unroll
      for (int i = 0; i < 2; ++i)
        gload_lds16(sa[mh][i] + t * 64, &As[p][mh][i * 4096 + wid * 512]);
#pragma unroll
    for (int i = 0; i < 3; ++i)
      gload_lds16(sw3[i] + t * 64, &Ws[p][i * 4096 + wid * 512]);
  };

  issue(0, 0);
  for (int t = 0; t < nk; ++t) {
    const int p = t & 1;
    if (t + 1 < nk) {
      issue(t + 1, p ^ 1);  // next tile: 7 loads stay in flight across compute
      asm volatile("s_waitcnt vmcnt(7)" ::: "memory");  // tile t's 7 landed
    } else {
      asm volatile("s_waitcnt vmcnt(0)" ::: "memory");
    }
    __builtin_amdgcn_sched_barrier(0);
    __builtin_amdgcn_s_barrier();   // B1: all waves' tile-t stages visible
    __builtin_amdgcn_sched_barrier(0);

    const u16* Ab = &As[p][wm][0];
    const u16* Wb = &Ws[p][0];

    short8 af[4][2], bf[3][2];
    // B frags (cols wn*48 + {0,16,32}), reused across both phases
#pragma unroll
    for (int ni = 0; ni < 3; ++ni)
#pragma unroll
      for (int ks = 0; ks < 2; ++ks) {
        int rh = wn * 48 + ni * 16 + l15;
        bf[ni][ks] = *(const short8*)&Wb[rh * 64 + (((ks * 4 + lh) ^ (rh & 7)) << 3)];
      }
    // ---- phase 0: A lo half
#pragma unroll
    for (int mi = 0; mi < 4; ++mi)
#pragma unroll
      for (int ks = 0; ks < 2; ++ks) {
        int rh = mi * 16 + l15;
        af[mi][ks] = *(const short8*)&Ab[rh * 64 + (((ks * 4 + lh) ^ (rh & 7)) << 3)];
      }
    __builtin_amdgcn_s_setprio(1);
#pragma unroll
    for (int mi = 0; mi < 4; ++mi)
#pragma unroll
      for (int ni = 0; ni < 3; ++ni)
#pragma unroll
        for (int ks = 0; ks < 2; ++ks)
          acc[mi][ni] = mfma_bf16(af[mi][ks], bf[ni][ks], acc[mi][ni]);
    __builtin_amdgcn_s_setprio(0);
    // (mid-phase barrier removed: phase-1 ds_reads pipeline under phase-0 MFMA)
    // ---- phase 1: A hi half
#pragma unroll
    for (int mi = 0; mi < 4; ++mi)
#pragma unroll
      for (int ks = 0; ks < 2; ++ks) {
        int rh = (4 + mi) * 16 + l15;
        af[mi][ks] = *(const short8*)&Ab[rh * 64 + (((ks * 4 + lh) ^ (rh & 7)) << 3)];
      }
    __builtin_amdgcn_s_setprio(1);
#pragma unroll
    for (int mi = 0; mi < 4; ++mi)
#pragma unroll
      for (int ni = 0; ni < 3; ++ni)
#pragma unroll
        for (int ks = 0; ks < 2; ++ks)
          acc[4 + mi][ni] = mfma_bf16(af[mi][ks], bf[ni][ks], acc[4 + mi][ni]);
    __builtin_amdgcn_s_setprio(0);

    // B2: all reads of buf[p] complete before iter t+2's issue overwrites it
    asm volatile("s_waitcnt lgkmcnt(0)" ::: "memory");
    __builtin_amdgcn_sched_barrier(0);
    __builtin_amdgcn_s_barrier();
    __builtin_amdgcn_sched_barrier(0);
  }

  // ---- epilogue (bf16)
#pragma unroll
  for (int mi = 0; mi < 8; ++mi)
#pragma unroll
    for (int ni = 0; ni < 3; ++ni)
#pragma unroll
      for (int j = 0; j < 4; ++j) {
        int row = brow + wm * 128 + mi * 16 + lh * 4 + j;
        int col = bcol + wn * 48 + ni * 16 + l15;
        C[(size_t)row * N + col] = f2b(acc[mi][ni][j]);
      }
}

// ---------- 256x128 counted-vmcnt GEMM (WO projection, fp32 out) ----------
// Mid-phase barrier removed (same rationale as gemm_qkv).
__global__ __launch_bounds__(512, 2) void gemm_wo(const u16* __restrict__ A,
                                                  const u16* __restrict__ W,
                                                  float* __restrict__ C,
                                                  int M, int N, int K) {
  __shared__ __align__(16) u16 As[2][2][128 * 64];  // [buf][half][r*64+swz] 64KB
  __shared__ __align__(16) u16 Ws[2][128 * 64];     // [buf][r*64+swz]       32KB

  const int tid = threadIdx.x, lane = tid & 63, wid = tid >> 6;
  const int wm = wid >> 2, wn = wid & 3;
  const int l15 = lane & 15, lh = lane >> 4;

  // T1 bijective XCD swizzle (nwg = 256, %8 == 0)
  const int nwg = gridDim.x * gridDim.y;
  const int lin = blockIdx.y * gridDim.x + blockIdx.x;
  const int swz = (lin & 7) * (nwg >> 3) + (lin >> 3);
  const int brow = (swz / gridDim.x) * 256, bcol = (swz % gridDim.x) * 128;

  const int srp = wid * 8 + (lane >> 3);
  const int gsw = ((lane & 7) ^ (lane >> 3)) << 3;
  const u16* sa[2][2];
  const u16* sw2[2];
#pragma unroll
  for (int mh = 0; mh < 2; ++mh)
#pragma unroll
    for (int i = 0; i < 2; ++i)
      sa[mh][i] = A + (size_t)(brow + mh * 128 + i * 64 + srp) * K + gsw;
#pragma unroll
  for (int i = 0; i < 2; ++i)
    sw2[i] = W + (size_t)(bcol + i * 64 + srp) * K + gsw;

  f32x4 acc[8][2];
#pragma unroll
  for (int mi = 0; mi < 8; ++mi)
#pragma unroll
    for (int ni = 0; ni < 2; ++ni) acc[mi][ni] = (f32x4)0.0f;

  const int nk = K >> 6;

  auto issue = [&](int t, int p) {
#pragma unroll
    for (int mh = 0; mh < 2; ++mh)
#pragma unroll
      for (int i = 0; i < 2; ++i)
        gload_lds16(sa[mh][i] + t * 64, &As[p][mh][i * 4096 + wid * 512]);
#pragma unroll
    for (int i = 0; i < 2; ++i)
      gload_lds16(sw2[i] + t * 64, &Ws[p][i * 4096 + wid * 512]);
  };

  issue(0, 0);
  for (int t = 0; t < nk; ++t) {
    const int p = t & 1;
    if (t + 1 < nk) {
      issue(t + 1, p ^ 1);  // 6 loads for tile t+1 stay in flight
      asm volatile("s_waitcnt vmcnt(6)" ::: "memory");  // tile t's 6 landed
    } else {
      asm volatile("s_waitcnt vmcnt(0)" ::: "memory");
    }
    __builtin_amdgcn_sched_barrier(0);
    __builtin_amdgcn_s_barrier();   // B1: tile-t stages visible
    __builtin_amdgcn_sched_barrier(0);

    const u16* Ab = &As[p][wm][0];
    const u16* Wb = &Ws[p][0];

    short8 af[4][2], bf[2][2];
    // B frags (cols wn*32 + {0,16}), reused across both phases
#pragma unroll
    for (int ni = 0; ni < 2; ++ni)
#pragma unroll
      for (int ks = 0; ks < 2; ++ks) {
        int rh = wn * 32 + ni * 16 + l15;
        bf[ni][ks] = *(const short8*)&Wb[rh * 64 + (((ks * 4 + lh) ^ (rh & 7)) << 3)];
      }
    // ---- phase 0: A lo half
#pragma unroll
    for (int mi = 0; mi < 4; ++mi)
#pragma unroll
      for (int ks = 0; ks < 2; ++ks) {
        int rh = mi * 16 + l15;
        af[mi][ks] = *(const short8*)&Ab[rh * 64 + (((ks * 4 + lh) ^ (rh & 7)) << 3)];
      }
    __builtin_amdgcn_s_setprio(1);
#pragma unroll
    for (int mi = 0; mi < 4; ++mi)
#pragma unroll
      for (int ni = 0; ni < 2; ++ni)
#pragma unroll
        for (int ks = 0; ks < 2; ++ks)
          acc[mi][ni] = mfma_bf16(af[mi][ks], bf[ni][ks], acc[mi][ni]);
    __builtin_amdgcn_s_setprio(0);
    // (mid-phase barrier removed)
    // ---- phase 1: A hi half
#pragma unroll
    for (int mi = 0; mi < 4; ++mi)
#pragma unroll
      for (int ks = 0; ks < 2; ++ks) {
        int rh = (4 + mi) * 16 + l15;
        af[mi][ks] = *(const short8*)&Ab[rh * 64 + (((ks * 4 + lh) ^ (rh & 7)) << 3)];
      }
    __builtin_amdgcn_s_setprio(1);
#pragma unroll
    for (int mi = 0; mi < 4; ++mi)
#pragma unroll
      for (int ni = 0; ni < 2; ++ni)
#pragma unroll
        for (int ks = 0; ks < 2; ++ks)
          acc[4 + mi][ni] = mfma_bf16(af[mi][ks], bf[ni][ks], acc[4 + mi][ni]);
    __builtin_amdgcn_s_setprio(0);

    // B2: all reads of buf[p] complete before iter t+2's issue overwrites it
    asm volatile("s_waitcnt lgkmcnt(0)" ::: "memory");
    __builtin_amdgcn_sched_barrier(0);
    __builtin_amdgcn_s_barrier();
    __builtin_amdgcn_sched_barrier(0);
  }

  // ---- epilogue (fp32)
#pragma unroll
  for (int mi = 0; mi < 8; ++mi)
#pragma unroll
    for (int ni = 0; ni < 2; ++ni)
#pragma unroll
      for (int j = 0; j < 4; ++j) {
        int row = brow + wm * 128 + mi * 16 + lh * 4 + j;
        int col = bcol + wn * 32 + ni * 16 + l15;
        C[(size_t)row * N + col] = acc[mi][ni][j];
      }
}

// ---------- fused causal GQA flash attention (best measured: 91.2 µs) ----------
// 256 blocks x 8 waves (512 thr), complementary q-tile pairing (qp, 15-qp)
// — optimal: pairs the max-work stream with the min-work stream so the
// makespan block's SIMDs are not oversubscribed (R14 lesson). Swapped QK^T
// softmax, T14 reg-staging (two barriers/tile — both cheaper variants
// measured worse: R0-style x2-calls and R16 dbuf/gload_lds), KVBLK=128.
#define QBLK 128
#define KVBLK 128

static __device__ __forceinline__ void attn_tile(
    const short8* qa, f32x4* o, float& l, float& m,
    int qrow0, int kv0,
    const u16* Ks, const unsigned* Vt32, u16* myP,
    int l15, int lh) {
  if (kv0 > qrow0 + 15) return;   // fully masked for this wave

  // ---- swapped QK^T: st[nt][j] = S[kv = kv0+nt*16+lh*4+j][q = qrow0+l15]
  f32x4 st[4];
#pragma unroll
  for (int nt = 0; nt < 4; ++nt) st[nt] = (f32x4)0.0f;
  __builtin_amdgcn_s_setprio(1);
#pragma unroll
  for (int nt = 0; nt < 4; ++nt) {
    const u16* krow = &Ks[(nt * 16 + l15) * 136 + (lh << 3)];
#pragma unroll
    for (int kk = 0; kk < 4; ++kk) {
      short8 kb = *(const short8*)(krow + kk * 32);
      st[nt] = mfma_bf16(kb, qa[kk], st[nt]);
    }
  }
  __builtin_amdgcn_s_setprio(0);

  // ---- causal mask: kv > q  <=>  (kv0 + lh*4 - qrow0 - l15) + nt*16 + j > 0
  const int kvq = kv0 + lh * 4 - qrow0 - l15;
#pragma unroll
  for (int nt = 0; nt < 4; ++nt)
#pragma unroll
    for (int j = 0; j < 4; ++j)
      if (kvq + nt * 16 + j > 0) st[nt][j] = -1e30f;

  // ---- in-lane row max (q = l15), then reduce across the 4 lh groups
  float mt = st[0][0];
#pragma unroll
  for (int nt = 0; nt < 4; ++nt)
#pragma unroll
    for (int j = 0; j < 4; ++j) mt = fmaxf(mt, st[nt][j]);
  mt = fmaxf(mt, __shfl_xor(mt, 16));
  mt = fmaxf(mt, __shfl_xor(mt, 32));

  // ---- defer-max (T13): rescale only when max grew by > 8
  if (!__all(mt - m <= 8.0f)) {
    float mn = fmaxf(m, mt);
    float a = __expf(m - mn);
    m = mn;
    l *= a;
    float aj[4];
#pragma unroll
    for (int j = 0; j < 4; ++j) aj[j] = __shfl(a, lh * 4 + j);
#pragma unroll
    for (int n = 0; n < 8; ++n)
#pragma unroll
      for (int j = 0; j < 4; ++j) o[n][j] *= aj[j];
  }

  // ---- P = exp(S - m); row-sum accumulated in-lane (partial over this lh)
  f32x4 p[4];
  float ps = 0.0f;
#pragma unroll
  for (int nt = 0; nt < 4; ++nt) {
#pragma unroll
    for (int j = 0; j < 4; ++j) p[nt][j] = __expf(st[nt][j] - m);
    ps += (p[nt][0] + p[nt][1]) + (p[nt][2] + p[nt][3]);
  }
  l += ps;

  // ---- P -> per-wave LDS, pair-packed b32 at elem l15*72 + kv
  unsigned* P32 = (unsigned*)myP;
  const int pb = l15 * 36 + lh * 2;
#pragma unroll
  for (int nt = 0; nt < 4; ++nt)
#pragma unroll
    for (int jj = 0; jj < 2; ++jj)
      P32[pb + nt * 8 + jj] =
          (unsigned)f2b(p[nt][2 * jj]) | ((unsigned)f2b(p[nt][2 * jj + 1]) << 16);

  // ---- PV (read pattern unchanged from verified kernel)
  __builtin_amdgcn_s_setprio(1);
#pragma unroll
  for (int c = 0; c < 2; ++c) {
    short8 pa = *(const short8*)&myP[l15 * 72 + c * 32 + (lh << 3)];
#pragma unroll
    for (int nt2 = 0; nt2 < 8; ++nt2) {
      int d = nt2 * 16 + l15;
      int byteoff = (d * 144 + (c * 32 + lh * 8) * 2) ^ (((d >> 3) & 7) << 4);
      short8 vb = *(const short8*)((const char*)Vt32 + byteoff);
      o[nt2] = mfma_bf16(pa, vb, o[nt2]);
    }
  }
  __builtin_amdgcn_s_setprio(0);
}

__global__ __launch_bounds__(512) void attn_kernel(const u16* __restrict__ QKV,
                                                   const float* __restrict__ rope,
                                                   u16* __restrict__ Y) {
  __shared__ __align__(16) u16 Ks[2][64 * 136];        // 2 x 17408 B
  __shared__ __align__(16) unsigned Vt32[2][128 * 36]; // 2 x 18432 B
  __shared__ __align__(16) u16 Ps[8][16 * 72];         // 18432 B

  const int tid = threadIdx.x, lane = tid & 63, wid = tid >> 6;
  const int l15 = lane & 15, lh = lane >> 4;
  const int bid = blockIdx.x;
  const int qpair = bid & 7;
  const int h = (bid >> 3) & 15;
  const int b = bid >> 7;
  const int kvh = h >> 2;
  const int qtA = qpair, qtB = 15 - qpair;
  const int rowA = qtA * QBLK + wid * 16;
  const int rowB = qtB * QBLK + wid * 16;

  const u16* Kb_ = QKV + (size_t)b * TT * QSTR + DD + kvh * HD;  // K cols
  const u16* Vb_ = Kb_ + NKVH * HD;                              // V cols

  short8 qaA[4], qaB[4];
  {
    const u16* qA = QKV + (size_t)(b * TT + rowA + l15) * QSTR + h * HD + (lh << 3);
    const u16* qB = QKV + (size_t)(b * TT + rowB + l15) * QSTR + h * HD + (lh << 3);
#pragma unroll
    for (int kk = 0; kk < 4; ++kk) {
      qaA[kk] = *(const short8*)(qA + kk * 32);
      qaB[kk] = *(const short8*)(qB + kk * 32);
    }
  }
  // ---- fused Q-RoPE + softmax scale (pair (i, i+64) = qa[kk] / qa[kk+2])
  {
    const float* rpA = rope + (size_t)(rowA + l15) * 128;
    const float* rpB = rope + (size_t)(rowB + l15) * 128;
#pragma unroll
    for (int kk = 0; kk < 2; ++kk)
#pragma unroll
      for (int e = 0; e < 8; ++e) {
        const int i2 = 2 * (kk * 32 + (lh << 3) + e);
        float c = rpA[i2], s = rpA[i2 + 1];
        float x1 = b2f((u16)qaA[kk][e]), x2 = b2f((u16)qaA[kk + 2][e]);
        qaA[kk][e]     = (short)f2b(QSCALE * (x1 * c - x2 * s));
        qaA[kk + 2][e] = (short)f2b(QSCALE * (x1 * s + x2 * c));
        float cb = rpB[i2], sb = rpB[i2 + 1];
        float y1 = b2f((u16)qaB[kk][e]), y2 = b2f((u16)qaB[kk + 2][e]);
        qaB[kk][e]     = (short)f2b(QSCALE * (y1 * cb - y2 * sb));
        qaB[kk + 2][e] = (short)f2b(QSCALE * (y1 * sb + y2 * cb));
      }
  }

  f32x4 oA[8], oB[8];
  float lA = 0.0f, lB = 0.0f;
  float mA = -1e30f, mB = -1e30f;
#pragma unroll
  for (int n = 0; n < 8; ++n) { oA[n] = (f32x4)0.0f; oB[n] = (f32x4)0.0f; }

  const int kvend = (qtB + 1) * QBLK;   // multiple of 128

  // staging registers (T14: issue early, write late); 128 KV rows per pass
  short8 kreg[4], vreg[4];
  const int srow = tid >> 4;           // 0..31
  const int sc8 = (tid & 15) << 3;

  auto issue = [&](int kv0) {
    kreg[0] = *(const short8*)&Kb_[(size_t)(kv0 + srow) * QSTR + sc8];
    kreg[1] = *(const short8*)&Kb_[(size_t)(kv0 + 32 + srow) * QSTR + sc8];
    kreg[2] = *(const short8*)&Kb_[(size_t)(kv0 + 64 + srow) * QSTR + sc8];
    kreg[3] = *(const short8*)&Kb_[(size_t)(kv0 + 96 + srow) * QSTR + sc8];
    vreg[0] = *(const short8*)&Vb_[(size_t)(kv0 + 2 * srow) * QSTR + sc8];
    vreg[1] = *(const short8*)&Vb_[(size_t)(kv0 + 2 * srow + 1) * QSTR + sc8];
    vreg[2] = *(const short8*)&Vb_[(size_t)(kv0 + 64 + 2 * srow) * QSTR + sc8];
    vreg[3] = *(const short8*)&Vb_[(size_t)(kv0 + 64 + 2 * srow + 1) * QSTR + sc8];
  };

  issue(0);
  for (int kv0 = 0; kv0 < kvend; kv0 += KVBLK) {
    __syncthreads();   // previous tile's LDS reads done
    *(short8*)&Ks[0][srow * 136 + sc8] = kreg[0];
    *(short8*)&Ks[0][(srow + 32) * 136 + sc8] = kreg[1];
    *(short8*)&Ks[1][srow * 136 + sc8] = kreg[2];
    *(short8*)&Ks[1][(srow + 32) * 136 + sc8] = kreg[3];
#pragma unroll
    for (int e = 0; e < 8; ++e) {
      int d = sc8 + e;
      unsigned pk0 = (unsigned)(u16)vreg[0][e] | ((unsigned)(u16)vreg[1][e] << 16);
      unsigned pk1 = (unsigned)(u16)vreg[2][e] | ((unsigned)(u16)vreg[3][e] << 16);
      int byteoff = (d * 144 + 4 * srow) ^ (((d >> 3) & 7) << 4);
      *(unsigned*)((char*)&Vt32[0][0] + byteoff) = pk0;
      *(unsigned*)((char*)&Vt32[1][0] + byteoff) = pk1;
    }
    __syncthreads();   // staged tile visible
    if (kv0 + KVBLK < kvend) issue(kv0 + KVBLK);  // overlap next loads with compute

    attn_tile(qaA, oA, lA, mA, rowA, kv0,      &Ks[0][0], &Vt32[0][0], &Ps[wid][0], l15, lh);
    attn_tile(qaA, oA, lA, mA, rowA, kv0 + 64, &Ks[1][0], &Vt32[1][0], &Ps[wid][0], l15, lh);
    attn_tile(qaB, oB, lB, mB, rowB, kv0,      &Ks[0][0], &Vt32[0][0], &Ps[wid][0], l15, lh);
    attn_tile(qaB, oB, lB, mB, rowB, kv0 + 64, &Ks[1][0], &Vt32[1][0], &Ps[wid][0], l15, lh);
  }

  // ---- epilogue: total row-sums (reduce over lh), redistribute to q=lh*4+j
  lA += __shfl_xor(lA, 16); lA += __shfl_xor(lA, 32);
  lB += __shfl_xor(lB, 16); lB += __shfl_xor(lB, 32);
  f32x4 invA, invB;
#pragma unroll
  for (int j = 0; j < 4; ++j) {
    invA[j] = __builtin_amdgcn_rcpf(__shfl(lA, lh * 4 + j));
    invB[j] = __builtin_amdgcn_rcpf(__shfl(lB, lh * 4 + j));
  }
#pragma unroll
  for (int nt = 0; nt < 8; ++nt)
#pragma unroll
    for (int j = 0; j < 4; ++j) {
      Y[(size_t)(b * TT + rowA + lh * 4 + j) * DD + h * HD + nt * 16 + l15] =
          f2b(oA[nt][j] * invA[j]);
      Y[(size_t)(b * TT + rowB + lh * 4 + j) * DD + h * HD + nt * 16 + l15] =
          f2b(oB[nt][j] * invB[j]);
    }
}

// ---------- launcher ----------
extern "C" void kernel_launch(void* const* d_in, const int* in_sizes, int n_in,
                              void* d_out, int out_size, void* d_ws, size_t ws_size,
                              hipStream_t stream) {
  const float* x    = (const float*)d_in[0];
  const float* rope = (const float*)d_in[1];
  const float* wq   = (const float*)d_in[2];
  const float* wk   = (const float*)d_in[3];
  const float* wv   = (const float*)d_in[4];
  const float* wo   = (const float*)d_in[5];
  float* out = (float*)d_out;

  char* ws = (char*)d_ws;
  u16* xb    = (u16*)ws; ws += (size_t)MM * DD * 2;        // 16.8 MB
  u16* wqkvb = (u16*)ws; ws += (size_t)QSTR * DD * 2;      // 12.6 MB (wq|wk|wv rows)
  u16* wob   = (u16*)ws; ws += (size_t)DD * DD * 2;        //  8.4 MB
  u16* QKVb  = (u16*)ws; ws += (size_t)MM * QSTR * 2;      // 25.2 MB
  u16* Yb    = (u16*)ws;                                   // 16.8 MB

  // 1) fused converts: x, wq, wk, wv, wo in ONE launch (xb stays L3-warm)
  cvt_all<<<2048, 256, 0, stream>>>(x, wq, wk, wv, wo, xb, wqkvb, wob);

  // 2) fused QKV projection: 256x192 counted-vmcnt GEMM (256 blocks, 1/CU)
  gemm_qkv<<<dim3(QSTR / 192, MM / 256), 512, 0, stream>>>(xb, wqkvb, QKVb, MM, QSTR, DD);

  // 3) RoPE on K only (Q-rope fused into attention)
  rope_k<<<(MM * NKVH * 64) / 256, 256, 0, stream>>>(QKVb + DD, rope);

  // 4) attention (best measured: complementary pairing, 512 threads)
  attn_kernel<<<BB * NH * (TT / QBLK / 2), 512, 0, stream>>>(QKVb, rope, Yb);

  // 5) output projection: 256x128 counted-vmcnt GEMM (256 blocks, 1/CU)
  gemm_wo<<<dim3(DD / 128, MM / 256), 512, 0, stream>>>(Yb, wob, out, MM, DD, DD);
}

// Round 20
// 197.399 us; speedup vs baseline: 1.0278x; 1.0039x over previous
//
#include <hip/hip_runtime.h>

// ---------- types & helpers ----------
typedef unsigned short u16;
typedef float   f32x4  __attribute__((ext_vector_type(4)));
typedef short   short8 __attribute__((ext_vector_type(8)));
typedef __bf16  bf16x8 __attribute__((ext_vector_type(8)));
typedef float   float4v __attribute__((ext_vector_type(4)));
typedef unsigned short u16x4 __attribute__((ext_vector_type(4)));

// native HW bf16 convert (RNE) — do not hand-roll (T12/m240)
static __device__ __forceinline__ u16 f2b(float f) {
  return __builtin_bit_cast(u16, (__bf16)f);
}
static __device__ __forceinline__ float b2f(u16 h) {
  union { unsigned u; float f; } v; v.u = ((unsigned)h) << 16;
  return v.f;
}
static __device__ __forceinline__ f32x4 mfma_bf16(short8 a, short8 b, f32x4 c) {
  return __builtin_amdgcn_mfma_f32_16x16x32_bf16(
      __builtin_bit_cast(bf16x8, a), __builtin_bit_cast(bf16x8, b), c, 0, 0, 0);
}
// async global->LDS, 16B per lane; lds ptr must be wave-uniform base (HW adds lane*16)
static __device__ __forceinline__ void gload_lds16(const u16* g, u16* l) {
  __builtin_amdgcn_global_load_lds(
      (const __attribute__((address_space(1))) unsigned int*)g,
      (__attribute__((address_space(3))) unsigned int*)l, 16, 0, 0);
}

// ---------- problem constants ----------
#define BB 2
#define TT 2048
#define DD 2048
#define NH 16
#define NKVH 4
#define HD 128
#define MM (BB * TT)          // 4096 rows
#define QSTR 3072             // fused QKV projection row: [Q(2048) | K(512) | V(512)]
#define QSCALE 0.08838834764831845f

// ---------- fused fp32 -> bf16 convert (all 5 tensors, 1 launch) ----------
// NOTE (R18 lesson): converting x here and re-reading xb in gemm_qkv is
// nearly free — xb is L3-resident when gemm_qkv runs. Fusing the convert
// into the GEMM replaced warm bf16 reads with cold fp32 reads (2x bytes,
// 1.6x refetch) and cost +55 µs. Keep the round-trip.
#define N4_X   ((MM * DD) / 4)
#define N4_WQ  ((DD * DD) / 4)
#define N4_WKV ((NKVH * HD * DD) / 4)
#define N4_WO  ((DD * DD) / 4)
#define N4_TOT (N4_X + N4_WQ + 2 * N4_WKV + N4_WO)

__global__ __launch_bounds__(256) void cvt_all(const float* __restrict__ x,
                                               const float* __restrict__ wq,
                                               const float* __restrict__ wk,
                                               const float* __restrict__ wv,
                                               const float* __restrict__ wo,
                                               u16* __restrict__ xb,
                                               u16* __restrict__ wqkvb,
                                               u16* __restrict__ wob) {
  int stride = gridDim.x * blockDim.x;
  for (int i = blockIdx.x * blockDim.x + threadIdx.x; i < N4_TOT; i += stride) {
    const float4v* src;
    u16x4* dst;
    int off;
    if (i < N4_X) {
      src = (const float4v*)x; dst = (u16x4*)xb; off = i;
    } else if (i < N4_X + N4_WQ) {
      src = (const float4v*)wq; dst = (u16x4*)wqkvb; off = i - N4_X;
    } else if (i < N4_X + N4_WQ + N4_WKV) {
      src = (const float4v*)wk; dst = (u16x4*)wqkvb + N4_WQ; off = i - (N4_X + N4_WQ);
    } else if (i < N4_X + N4_WQ + 2 * N4_WKV) {
      src = (const float4v*)wv; dst = (u16x4*)wqkvb + N4_WQ + N4_WKV;
      off = i - (N4_X + N4_WQ + N4_WKV);
    } else {
      src = (const float4v*)wo; dst = (u16x4*)wob; off = i - (N4_X + N4_WQ + 2 * N4_WKV);
    }
    float4v v = src[off];
    u16x4 o;
    o[0] = f2b(v[0]); o[1] = f2b(v[1]); o[2] = f2b(v[2]); o[3] = f2b(v[3]);
    dst[off] = o;
  }
}

// ---------- RoPE on K only, 8-wide vectorized (G13) ----------
// Each thread handles 8 consecutive pairs (i0..i0+7, +64): 2 short8 loads,
// 4 float4 table loads (64B, L3-resident 1MB table), 2 short8 stores.
// Scalar version measured 3.1 TB/s (half of achievable) — classic
// Common-mistake #2. Math bit-identical (same f2b / pairing).
__global__ __launch_bounds__(256) void rope_k(u16* __restrict__ K,
                                              const float* __restrict__ rope) {
  int idx = blockIdx.x * 256 + threadIdx.x;   // MM*NKVH*8 threads
  int i0 = (idx & 7) << 3;                    // 0,8,...,56
  int h  = (idx >> 3) & (NKVH - 1);
  int bt = idx >> 5;
  int t  = bt & (TT - 1);
  size_t base = (size_t)bt * QSTR + h * HD + i0;
  short8 x1v = *(const short8*)&K[base];
  short8 x2v = *(const short8*)&K[base + 64];
  const float* rp = rope + t * 128 + 2 * i0;  // 16 consecutive floats
  float4v r0 = *(const float4v*)(rp);
  float4v r1 = *(const float4v*)(rp + 4);
  float4v r2 = *(const float4v*)(rp + 8);
  float4v r3 = *(const float4v*)(rp + 12);
  float cs[16];
  *(float4v*)&cs[0] = r0; *(float4v*)&cs[4] = r1;
  *(float4v*)&cs[8] = r2; *(float4v*)&cs[12] = r3;
  short8 o1, o2;
#pragma unroll
  for (int e = 0; e < 8; ++e) {
    float c = cs[2 * e], s = cs[2 * e + 1];
    float x1 = b2f((u16)x1v[e]);
    float x2 = b2f((u16)x2v[e]);
    o1[e] = (short)f2b(x1 * c - x2 * s);
    o2[e] = (short)f2b(x1 * s + x2 * c);
  }
  *(short8*)&K[base]      = o1;
  *(short8*)&K[base + 64] = o2;
}

// ---------- 256x192 counted-vmcnt GEMM (QKV projection, bf16 out) ----------
// Mid-phase barrier removed (no correctness role; B1 + B2 protect buffers) so
// phase-1's ds_reads pipeline under phase-0's MFMA.
__global__ __launch_bounds__(512) void gemm_qkv(const u16* __restrict__ A,
                                                const u16* __restrict__ W,
                                                u16* __restrict__ C,
                                                int M, int N, int K) {
  __shared__ __align__(16) u16 As[2][2][128 * 64];  // [buf][half][r*64+swz] 64KB
  __shared__ __align__(16) u16 Ws[2][192 * 64];     // [buf][r*64+swz]       48KB

  const int tid = threadIdx.x, lane = tid & 63, wid = tid >> 6;
  const int wm = wid >> 2, wn = wid & 3;
  const int l15 = lane & 15, lh = lane >> 4;

  // T1 bijective XCD swizzle (nwg = 256, %8 == 0)
  const int nwg = gridDim.x * gridDim.y;
  const int lin = blockIdx.y * gridDim.x + blockIdx.x;
  const int swz = (lin & 7) * (nwg >> 3) + (lin >> 3);
  const int brow = (swz / gridDim.x) * 256, bcol = (swz % gridDim.x) * 192;

  const int srp = wid * 8 + (lane >> 3);
  const int gsw = ((lane & 7) ^ (lane >> 3)) << 3;
  const u16* sa[2][2];
  const u16* sw3[3];
#pragma unroll
  for (int mh = 0; mh < 2; ++mh)
#pragma unroll
    for (int i = 0; i < 2; ++i)
      sa[mh][i] = A + (size_t)(brow + mh * 128 + i * 64 + srp) * K + gsw;
#pragma unroll
  for (int i = 0; i < 3; ++i)
    sw3[i] = W + (size_t)(bcol + i * 64 + srp) * K + gsw;

  f32x4 acc[8][3];
#pragma unroll
  for (int mi = 0; mi < 8; ++mi)
#pragma unroll
    for (int ni = 0; ni < 3; ++ni) acc[mi][ni] = (f32x4)0.0f;

  const int nk = K >> 6;  // 64-wide K tiles

  auto issue = [&](int t, int p) {
#pragma unroll
    for (int mh = 0; mh < 2; ++mh)
#pragma unroll
      for (int i = 0; i < 2; ++i)
        gload_lds16(sa[mh][i] + t * 64, &As[p][mh][i * 4096 + wid * 512]);
#pragma unroll
    for (int i = 0; i < 3; ++i)
      gload_lds16(sw3[i] + t * 64, &Ws[p][i * 4096 + wid * 512]);
  };

  issue(0, 0);
  for (int t = 0; t < nk; ++t) {
    const int p = t & 1;
    if (t + 1 < nk) {
      issue(t + 1, p ^ 1);  // next tile: 7 loads stay in flight across compute
      asm volatile("s_waitcnt vmcnt(7)" ::: "memory");  // tile t's 7 landed
    } else {
      asm volatile("s_waitcnt vmcnt(0)" ::: "memory");
    }
    __builtin_amdgcn_sched_barrier(0);
    __builtin_amdgcn_s_barrier();   // B1: all waves' tile-t stages visible
    __builtin_amdgcn_sched_barrier(0);

    const u16* Ab = &As[p][wm][0];
    const u16* Wb = &Ws[p][0];

    short8 af[4][2], bf[3][2];
    // B frags (cols wn*48 + {0,16,32}), reused across both phases
#pragma unroll
    for (int ni = 0; ni < 3; ++ni)
#pragma unroll
      for (int ks = 0; ks < 2; ++ks) {
        int rh = wn * 48 + ni * 16 + l15;
        bf[ni][ks] = *(const short8*)&Wb[rh * 64 + (((ks * 4 + lh) ^ (rh & 7)) << 3)];
      }
    // ---- phase 0: A lo half
#pragma unroll
    for (int mi = 0; mi < 4; ++mi)
#pragma unroll
      for (int ks = 0; ks < 2; ++ks) {
        int rh = mi * 16 + l15;
        af[mi][ks] = *(const short8*)&Ab[rh * 64 + (((ks * 4 + lh) ^ (rh & 7)) << 3)];
      }
    __builtin_amdgcn_s_setprio(1);
#pragma unroll
    for (int mi = 0; mi < 4; ++mi)
#pragma unroll
      for (int ni = 0; ni < 3; ++ni)
#pragma unroll
        for (int ks = 0; ks < 2; ++ks)
          acc[mi][ni] = mfma_bf16(af[mi][ks], bf[ni][ks], acc[mi][ni]);
    __builtin_amdgcn_s_setprio(0);
    // (mid-phase barrier removed: phase-1 ds_reads pipeline under phase-0 MFMA)
    // ---- phase 1: A hi half
#pragma unroll
    for (int mi = 0; mi < 4; ++mi)
#pragma unroll
      for (int ks = 0; ks < 2; ++ks) {
        int rh = (4 + mi) * 16 + l15;
        af[mi][ks] = *(const short8*)&Ab[rh * 64 + (((ks * 4 + lh) ^ (rh & 7)) << 3)];
      }
    __builtin_amdgcn_s_setprio(1);
#pragma unroll
    for (int mi = 0; mi < 4; ++mi)
#pragma unroll
      for (int ni = 0; ni < 3; ++ni)
#pragma unroll
        for (int ks = 0; ks < 2; ++ks)
          acc[4 + mi][ni] = mfma_bf16(af[mi][ks], bf[ni][ks], acc[4 + mi][ni]);
    __builtin_amdgcn_s_setprio(0);

    // B2: all reads of buf[p] complete before iter t+2's issue overwrites it
    asm volatile("s_waitcnt lgkmcnt(0)" ::: "memory");
    __builtin_amdgcn_sched_barrier(0);
    __builtin_amdgcn_s_barrier();
    __builtin_amdgcn_sched_barrier(0);
  }

  // ---- epilogue (bf16)
#pragma unroll
  for (int mi = 0; mi < 8; ++mi)
#pragma unroll
    for (int ni = 0; ni < 3; ++ni)
#pragma unroll
      for (int j = 0; j < 4; ++j) {
        int row = brow + wm * 128 + mi * 16 + lh * 4 + j;
        int col = bcol + wn * 48 + ni * 16 + l15;
        C[(size_t)row * N + col] = f2b(acc[mi][ni][j]);
      }
}

// ---------- 256x128 counted-vmcnt GEMM (WO projection, fp32 out) ----------
// Mid-phase barrier removed (same rationale as gemm_qkv).
__global__ __launch_bounds__(512, 2) void gemm_wo(const u16* __restrict__ A,
                                                  const u16* __restrict__ W,
                                                  float* __restrict__ C,
                                                  int M, int N, int K) {
  __shared__ __align__(16) u16 As[2][2][128 * 64];  // [buf][half][r*64+swz] 64KB
  __shared__ __align__(16) u16 Ws[2][128 * 64];     // [buf][r*64+swz]       32KB

  const int tid = threadIdx.x, lane = tid & 63, wid = tid >> 6;
  const int wm = wid >> 2, wn = wid & 3;
  const int l15 = lane & 15, lh = lane >> 4;

  // T1 bijective XCD swizzle (nwg = 256, %8 == 0)
  const int nwg = gridDim.x * gridDim.y;
  const int lin = blockIdx.y * gridDim.x + blockIdx.x;
  const int swz = (lin & 7) * (nwg >> 3) + (lin >> 3);
  const int brow = (swz / gridDim.x) * 256, bcol = (swz % gridDim.x) * 128;

  const int srp = wid * 8 + (lane >> 3);
  const int gsw = ((lane & 7) ^ (lane >> 3)) << 3;
  const u16* sa[2][2];
  const u16* sw2[2];
#pragma unroll
  for (int mh = 0; mh < 2; ++mh)
#pragma unroll
    for (int i = 0; i < 2; ++i)
      sa[mh][i] = A + (size_t)(brow + mh * 128 + i * 64 + srp) * K + gsw;
#pragma unroll
  for (int i = 0; i < 2; ++i)
    sw2[i] = W + (size_t)(bcol + i * 64 + srp) * K + gsw;

  f32x4 acc[8][2];
#pragma unroll
  for (int mi = 0; mi < 8; ++mi)
#pragma unroll
    for (int ni = 0; ni < 2; ++ni) acc[mi][ni] = (f32x4)0.0f;

  const int nk = K >> 6;

  auto issue = [&](int t, int p) {
#pragma unroll
    for (int mh = 0; mh < 2; ++mh)
#pragma unroll
      for (int i = 0; i < 2; ++i)
        gload_lds16(sa[mh][i] + t * 64, &As[p][mh][i * 4096 + wid * 512]);
#pragma unroll
    for (int i = 0; i < 2; ++i)
      gload_lds16(sw2[i] + t * 64, &Ws[p][i * 4096 + wid * 512]);
  };

  issue(0, 0);
  for (int t = 0; t < nk; ++t) {
    const int p = t & 1;
    if (t + 1 < nk) {
      issue(t + 1, p ^ 1);  // 6 loads for tile t+1 stay in flight
      asm volatile("s_waitcnt vmcnt(6)" ::: "memory");  // tile t's 6 landed
    } else {
      asm volatile("s_waitcnt vmcnt(0)" ::: "memory");
    }
    __builtin_amdgcn_sched_barrier(0);
    __builtin_amdgcn_s_barrier();   // B1: tile-t stages visible
    __builtin_amdgcn_sched_barrier(0);

    const u16* Ab = &As[p][wm][0];
    const u16* Wb = &Ws[p][0];

    short8 af[4][2], bf[2][2];
    // B frags (cols wn*32 + {0,16}), reused across both phases
#pragma unroll
    for (int ni = 0; ni < 2; ++ni)
#pragma unroll
      for (int ks = 0; ks < 2; ++ks) {
        int rh = wn * 32 + ni * 16 + l15;
        bf[ni][ks] = *(const short8*)&Wb[rh * 64 + (((ks * 4 + lh) ^ (rh & 7)) << 3)];
      }
    // ---- phase 0: A lo half
#pragma unroll
    for (int mi = 0; mi < 4; ++mi)
#pragma unroll
      for (int ks = 0; ks < 2; ++ks) {
        int rh = mi * 16 + l15;
        af[mi][ks] = *(const short8*)&Ab[rh * 64 + (((ks * 4 + lh) ^ (rh & 7)) << 3)];
      }
    __builtin_amdgcn_s_setprio(1);
#pragma unroll
    for (int mi = 0; mi < 4; ++mi)
#pragma unroll
      for (int ni = 0; ni < 2; ++ni)
#pragma unroll
        for (int ks = 0; ks < 2; ++ks)
          acc[mi][ni] = mfma_bf16(af[mi][ks], bf[ni][ks], acc[mi][ni]);
    __builtin_amdgcn_s_setprio(0);
    // (mid-phase barrier removed)
    // ---- phase 1: A hi half
#pragma unroll
    for (int mi = 0; mi < 4; ++mi)
#pragma unroll
      for (int ks = 0; ks < 2; ++ks) {
        int rh = (4 + mi) * 16 + l15;
        af[mi][ks] = *(const short8*)&Ab[rh * 64 + (((ks * 4 + lh) ^ (rh & 7)) << 3)];
      }
    __builtin_amdgcn_s_setprio(1);
#pragma unroll
    for (int mi = 0; mi < 4; ++mi)
#pragma unroll
      for (int ni = 0; ni < 2; ++ni)
#pragma unroll
        for (int ks = 0; ks < 2; ++ks)
          acc[4 + mi][ni] = mfma_bf16(af[mi][ks], bf[ni][ks], acc[4 + mi][ni]);
    __builtin_amdgcn_s_setprio(0);

    // B2: all reads of buf[p] complete before iter t+2's issue overwrites it
    asm volatile("s_waitcnt lgkmcnt(0)" ::: "memory");
    __builtin_amdgcn_sched_barrier(0);
    __builtin_amdgcn_s_barrier();
    __builtin_amdgcn_sched_barrier(0);
  }

  // ---- epilogue (fp32)
#pragma unroll
  for (int mi = 0; mi < 8; ++mi)
#pragma unroll
    for (int ni = 0; ni < 2; ++ni)
#pragma unroll
      for (int j = 0; j < 4; ++j) {
        int row = brow + wm * 128 + mi * 16 + lh * 4 + j;
        int col = bcol + wn * 32 + ni * 16 + l15;
        C[(size_t)row * N + col] = acc[mi][ni][j];
      }
}

// ---------- fused causal GQA flash attention (best measured: 91.2 µs) ----------
// 256 blocks x 8 waves (512 thr), complementary q-tile pairing (qp, 15-qp)
// — optimal: pairs the max-work stream with the min-work stream so the
// makespan block's SIMDs are not oversubscribed (R14 lesson). Swapped QK^T
// softmax, T14 reg-staging (two barriers/tile — both cheaper variants
// measured worse: R0-style x2-calls and R16 dbuf/gload_lds), KVBLK=128.
#define QBLK 128
#define KVBLK 128

static __device__ __forceinline__ void attn_tile(
    const short8* qa, f32x4* o, float& l, float& m,
    int qrow0, int kv0,
    const u16* Ks, const unsigned* Vt32, u16* myP,
    int l15, int lh) {
  if (kv0 > qrow0 + 15) return;   // fully masked for this wave

  // ---- swapped QK^T: st[nt][j] = S[kv = kv0+nt*16+lh*4+j][q = qrow0+l15]
  f32x4 st[4];
#pragma unroll
  for (int nt = 0; nt < 4; ++nt) st[nt] = (f32x4)0.0f;
  __builtin_amdgcn_s_setprio(1);
#pragma unroll
  for (int nt = 0; nt < 4; ++nt) {
    const u16* krow = &Ks[(nt * 16 + l15) * 136 + (lh << 3)];
#pragma unroll
    for (int kk = 0; kk < 4; ++kk) {
      short8 kb = *(const short8*)(krow + kk * 32);
      st[nt] = mfma_bf16(kb, qa[kk], st[nt]);
    }
  }
  __builtin_amdgcn_s_setprio(0);

  // ---- causal mask: kv > q  <=>  (kv0 + lh*4 - qrow0 - l15) + nt*16 + j > 0
  const int kvq = kv0 + lh * 4 - qrow0 - l15;
#pragma unroll
  for (int nt = 0; nt < 4; ++nt)
#pragma unroll
    for (int j = 0; j < 4; ++j)
      if (kvq + nt * 16 + j > 0) st[nt][j] = -1e30f;

  // ---- in-lane row max (q = l15), then reduce across the 4 lh groups
  float mt = st[0][0];
#pragma unroll
  for (int nt = 0; nt < 4; ++nt)
#pragma unroll
    for (int j = 0; j < 4; ++j) mt = fmaxf(mt, st[nt][j]);
  mt = fmaxf(mt, __shfl_xor(mt, 16));
  mt = fmaxf(mt, __shfl_xor(mt, 32));

  // ---- defer-max (T13): rescale only when max grew by > 8
  if (!__all(mt - m <= 8.0f)) {
    float mn = fmaxf(m, mt);
    float a = __expf(m - mn);
    m = mn;
    l *= a;
    float aj[4];
#pragma unroll
    for (int j = 0; j < 4; ++j) aj[j] = __shfl(a, lh * 4 + j);
#pragma unroll
    for (int n = 0; n < 8; ++n)
#pragma unroll
      for (int j = 0; j < 4; ++j) o[n][j] *= aj[j];
  }

  // ---- P = exp(S - m); row-sum accumulated in-lane (partial over this lh)
  f32x4 p[4];
  float ps = 0.0f;
#pragma unroll
  for (int nt = 0; nt < 4; ++nt) {
#pragma unroll
    for (int j = 0; j < 4; ++j) p[nt][j] = __expf(st[nt][j] - m);
    ps += (p[nt][0] + p[nt][1]) + (p[nt][2] + p[nt][3]);
  }
  l += ps;

  // ---- P -> per-wave LDS, pair-packed b32 at elem l15*72 + kv
  unsigned* P32 = (unsigned*)myP;
  const int pb = l15 * 36 + lh * 2;
#pragma unroll
  for (int nt = 0; nt < 4; ++nt)
#pragma unroll
    for (int jj = 0; jj < 2; ++jj)
      P32[pb + nt * 8 + jj] =
          (unsigned)f2b(p[nt][2 * jj]) | ((unsigned)f2b(p[nt][2 * jj + 1]) << 16);

  // ---- PV (read pattern unchanged from verified kernel)
  __builtin_amdgcn_s_setprio(1);
#pragma unroll
  for (int c = 0; c < 2; ++c) {
    short8 pa = *(const short8*)&myP[l15 * 72 + c * 32 + (lh << 3)];
#pragma unroll
    for (int nt2 = 0; nt2 < 8; ++nt2) {
      int d = nt2 * 16 + l15;
      int byteoff = (d * 144 + (c * 32 + lh * 8) * 2) ^ (((d >> 3) & 7) << 4);
      short8 vb = *(const short8*)((const char*)Vt32 + byteoff);
      o[nt2] = mfma_bf16(pa, vb, o[nt2]);
    }
  }
  __builtin_amdgcn_s_setprio(0);
}

__global__ __launch_bounds__(512) void attn_kernel(const u16* __restrict__ QKV,
                                                   const float* __restrict__ rope,
                                                   u16* __restrict__ Y) {
  __shared__ __align__(16) u16 Ks[2][64 * 136];        // 2 x 17408 B
  __shared__ __align__(16) unsigned Vt32[2][128 * 36]; // 2 x 18432 B
  __shared__ __align__(16) u16 Ps[8][16 * 72];         // 18432 B

  const int tid = threadIdx.x, lane = tid & 63, wid = tid >> 6;
  const int l15 = lane & 15, lh = lane >> 4;
  const int bid = blockIdx.x;
  const int qpair = bid & 7;
  const int h = (bid >> 3) & 15;
  const int b = bid >> 7;
  const int kvh = h >> 2;
  const int qtA = qpair, qtB = 15 - qpair;
  const int rowA = qtA * QBLK + wid * 16;
  const int rowB = qtB * QBLK + wid * 16;

  const u16* Kb_ = QKV + (size_t)b * TT * QSTR + DD + kvh * HD;  // K cols
  const u16* Vb_ = Kb_ + NKVH * HD;                              // V cols

  short8 qaA[4], qaB[4];
  {
    const u16* qA = QKV + (size_t)(b * TT + rowA + l15) * QSTR + h * HD + (lh << 3);
    const u16* qB = QKV + (size_t)(b * TT + rowB + l15) * QSTR + h * HD + (lh << 3);
#pragma unroll
    for (int kk = 0; kk < 4; ++kk) {
      qaA[kk] = *(const short8*)(qA + kk * 32);
      qaB[kk] = *(const short8*)(qB + kk * 32);
    }
  }
  // ---- fused Q-RoPE + softmax scale (pair (i, i+64) = qa[kk] / qa[kk+2])
  {
    const float* rpA = rope + (size_t)(rowA + l15) * 128;
    const float* rpB = rope + (size_t)(rowB + l15) * 128;
#pragma unroll
    for (int kk = 0; kk < 2; ++kk)
#pragma unroll
      for (int e = 0; e < 8; ++e) {
        const int i2 = 2 * (kk * 32 + (lh << 3) + e);
        float c = rpA[i2], s = rpA[i2 + 1];
        float x1 = b2f((u16)qaA[kk][e]), x2 = b2f((u16)qaA[kk + 2][e]);
        qaA[kk][e]     = (short)f2b(QSCALE * (x1 * c - x2 * s));
        qaA[kk + 2][e] = (short)f2b(QSCALE * (x1 * s + x2 * c));
        float cb = rpB[i2], sb = rpB[i2 + 1];
        float y1 = b2f((u16)qaB[kk][e]), y2 = b2f((u16)qaB[kk + 2][e]);
        qaB[kk][e]     = (short)f2b(QSCALE * (y1 * cb - y2 * sb));
        qaB[kk + 2][e] = (short)f2b(QSCALE * (y1 * sb + y2 * cb));
      }
  }

  f32x4 oA[8], oB[8];
  float lA = 0.0f, lB = 0.0f;
  float mA = -1e30f, mB = -1e30f;
#pragma unroll
  for (int n = 0; n < 8; ++n) { oA[n] = (f32x4)0.0f; oB[n] = (f32x4)0.0f; }

  const int kvend = (qtB + 1) * QBLK;   // multiple of 128

  // staging registers (T14: issue early, write late); 128 KV rows per pass
  short8 kreg[4], vreg[4];
  const int srow = tid >> 4;           // 0..31
  const int sc8 = (tid & 15) << 3;

  auto issue = [&](int kv0) {
    kreg[0] = *(const short8*)&Kb_[(size_t)(kv0 + srow) * QSTR + sc8];
    kreg[1] = *(const short8*)&Kb_[(size_t)(kv0 + 32 + srow) * QSTR + sc8];
    kreg[2] = *(const short8*)&Kb_[(size_t)(kv0 + 64 + srow) * QSTR + sc8];
    kreg[3] = *(const short8*)&Kb_[(size_t)(kv0 + 96 + srow) * QSTR + sc8];
    vreg[0] = *(const short8*)&Vb_[(size_t)(kv0 + 2 * srow) * QSTR + sc8];
    vreg[1] = *(const short8*)&Vb_[(size_t)(kv0 + 2 * srow + 1) * QSTR + sc8];
    vreg[2] = *(const short8*)&Vb_[(size_t)(kv0 + 64 + 2 * srow) * QSTR + sc8];
    vreg[3] = *(const short8*)&Vb_[(size_t)(kv0 + 64 + 2 * srow + 1) * QSTR + sc8];
  };

  issue(0);
  for (int kv0 = 0; kv0 < kvend; kv0 += KVBLK) {
    __syncthreads();   // previous tile's LDS reads done
    *(short8*)&Ks[0][srow * 136 + sc8] = kreg[0];
    *(short8*)&Ks[0][(srow + 32) * 136 + sc8] = kreg[1];
    *(short8*)&Ks[1][srow * 136 + sc8] = kreg[2];
    *(short8*)&Ks[1][(srow + 32) * 136 + sc8] = kreg[3];
#pragma unroll
    for (int e = 0; e < 8; ++e) {
      int d = sc8 + e;
      unsigned pk0 = (unsigned)(u16)vreg[0][e] | ((unsigned)(u16)vreg[1][e] << 16);
      unsigned pk1 = (unsigned)(u16)vreg[2][e] | ((unsigned)(u16)vreg[3][e] << 16);
      int byteoff = (d * 144 + 4 * srow) ^ (((d >> 3) & 7) << 4);
      *(unsigned*)((char*)&Vt32[0][0] + byteoff) = pk0;
      *(unsigned*)((char*)&Vt32[1][0] + byteoff) = pk1;
    }
    __syncthreads();   // staged tile visible
    if (kv0 + KVBLK < kvend) issue(kv0 + KVBLK);  // overlap next loads with compute

    attn_tile(qaA, oA, lA, mA, rowA, kv0,      &Ks[0][0], &Vt32[0][0], &Ps[wid][0], l15, lh);
    attn_tile(qaA, oA, lA, mA, rowA, kv0 + 64, &Ks[1][0], &Vt32[1][0], &Ps[wid][0], l15, lh);
    attn_tile(qaB, oB, lB, mB, rowB, kv0,      &Ks[0][0], &Vt32[0][0], &Ps[wid][0], l15, lh);
    attn_tile(qaB, oB, lB, mB, rowB, kv0 + 64, &Ks[1][0], &Vt32[1][0], &Ps[wid][0], l15, lh);
  }

  // ---- epilogue: total row-sums (reduce over lh), redistribute to q=lh*4+j
  lA += __shfl_xor(lA, 16); lA += __shfl_xor(lA, 32);
  lB += __shfl_xor(lB, 16); lB += __shfl_xor(lB, 32);
  f32x4 invA, invB;
#pragma unroll
  for (int j = 0; j < 4; ++j) {
    invA[j] = __builtin_amdgcn_rcpf(__shfl(lA, lh * 4 + j));
    invB[j] = __builtin_amdgcn_rcpf(__shfl(lB, lh * 4 + j));
  }
#pragma unroll
  for (int nt = 0; nt < 8; ++nt)
#pragma unroll
    for (int j = 0; j < 4; ++j) {
      Y[(size_t)(b * TT + rowA + lh * 4 + j) * DD + h * HD + nt * 16 + l15] =
          f2b(oA[nt][j] * invA[j]);
      Y[(size_t)(b * TT + rowB + lh * 4 + j) * DD + h * HD + nt * 16 + l15] =
          f2b(oB[nt][j] * invB[j]);
    }
}

// ---------- launcher ----------
extern "C" void kernel_launch(void* const* d_in, const int* in_sizes, int n_in,
                              void* d_out, int out_size, void* d_ws, size_t ws_size,
                              hipStream_t stream) {
  const float* x    = (const float*)d_in[0];
  const float* rope = (const float*)d_in[1];
  const float* wq   = (const float*)d_in[2];
  const float* wk   = (const float*)d_in[3];
  const float* wv   = (const float*)d_in[4];
  const float* wo   = (const float*)d_in[5];
  float* out = (float*)d_out;

  char* ws = (char*)d_ws;
  u16* xb    = (u16*)ws; ws += (size_t)MM * DD * 2;        // 16.8 MB
  u16* wqkvb = (u16*)ws; ws += (size_t)QSTR * DD * 2;      // 12.6 MB (wq|wk|wv rows)
  u16* wob   = (u16*)ws; ws += (size_t)DD * DD * 2;        //  8.4 MB
  u16* QKVb  = (u16*)ws; ws += (size_t)MM * QSTR * 2;      // 25.2 MB
  u16* Yb    = (u16*)ws;                                   // 16.8 MB

  // 1) fused converts: x, wq, wk, wv, wo in ONE launch (xb stays L3-warm)
  cvt_all<<<2048, 256, 0, stream>>>(x, wq, wk, wv, wo, xb, wqkvb, wob);

  // 2) fused QKV projection: 256x192 counted-vmcnt GEMM (256 blocks, 1/CU)
  gemm_qkv<<<dim3(QSTR / 192, MM / 256), 512, 0, stream>>>(xb, wqkvb, QKVb, MM, QSTR, DD);

  // 3) RoPE on K only, 8-wide vectorized (Q-rope fused into attention)
  rope_k<<<(MM * NKVH * 8) / 256, 256, 0, stream>>>(QKVb + DD, rope);

  // 4) attention (best measured: complementary pairing, 512 threads)
  attn_kernel<<<BB * NH * (TT / QBLK / 2), 512, 0, stream>>>(QKVb, rope, Yb);

  // 5) output projection: 256x128 counted-vmcnt GEMM (256 blocks, 1/CU)
  gemm_wo<<<dim3(DD / 128, MM / 256), 512, 0, stream>>>(Yb, wob, out, MM, DD, DD);
}